// Round 7
// baseline (298.864 us; speedup 1.0000x reference)
//
#include <hip/hip_runtime.h>
#include <stdint.h>

#define C96   96
#define TOTEL 25165824L   // 8*128*256*96

typedef __attribute__((ext_vector_type(16))) float f32x16;
typedef __attribute__((ext_vector_type(8)))  short short8;

// ---- LDS layout (bytes). Tile rows stride 208 B (104 bf16). Pad [192..207]={mu,rs}.
#define QL_OFF  0         // Q_l (raw X_l during stage) [256][208] = 53248
#define QR_OFF  53248     // Q_r [256][208] = 53248
#define XT0_OFF 106496    // raw V-source tile buf0 [64][208] = 13312
#define XT1_OFF 119808    // buf1
#define VT0_OFF 133120    // V^T bf16 [96][144B] = 13824, buf0
#define VT1_OFF 146944    // buf1 -> end 160768
// phase-1 overlay (temporally disjoint):
#define W1Q_OFF 106496    // W1 q-side bf16 [96][208]
#define W1K_OFF 126464    // W1 K-side bf16 [96][208]
#define LDS_SZ  160768    // 1 block/CU (LDS-bound) -> 2 waves/EU fixed

#define MFMA32(a,b,c) __builtin_amdgcn_mfma_f32_32x32x16_bf16(a,b,c,0,0,0)

__device__ __forceinline__ uint32_t cvtpk(float lo, float hi) {
    uint32_t d;
    asm("v_cvt_pk_bf16_f32 %0, %1, %2" : "=v"(d) : "v"(lo), "v"(hi));
    return d;
}
__device__ __forceinline__ float fexp2(float x) {       // 2^x (v_exp_f32 is base-2)
    float r; asm("v_exp_f32 %0, %1" : "=v"(r) : "v"(x)); return r;
}
__device__ __forceinline__ float bl(uint32_t u){ union{uint32_t i;float f;}a; a.i=u<<16;        return a.f; }
__device__ __forceinline__ float bh(uint32_t u){ union{uint32_t i;float f;}a; a.i=u&0xffff0000u; return a.f; }

union F8 { uint32_t u[4]; short8 s; uint4 q; };

// ---- staging split (T14): issue loads early, commit (cvt+ds_write) late ----
__device__ __forceinline__ void stage_issue(const float* __restrict__ src, int t,
                                            float4& a0, float4& a1, float4& a2) {
    a0 = *(const float4*)(src + (size_t)(0 * 512 + t) * 4);
    a1 = *(const float4*)(src + (size_t)(1 * 512 + t) * 4);
    a2 = *(const float4*)(src + (size_t)(2 * 512 + t) * 4);
}
__device__ __forceinline__ void stage_commit(char* dst, int t,
                                             const float4& a0, const float4& a1, const float4& a2) {
#pragma unroll
    for (int i = 0; i < 3; ++i) {
        const float4 v = (i == 0) ? a0 : (i == 1) ? a1 : a2;
        const int idx4 = i * 512 + t;
        const int r = idx4 / 24, c = (idx4 % 24) * 4;
        uint2 p; p.x = cvtpk(v.x, v.y); p.y = cvtpk(v.z, v.w);
        *(uint2*)(dst + r * 208 + c * 2) = p;
    }
}
// full stage (phase 1, 12 iters)
template<int ITERS>
__device__ __forceinline__ void stage(const float* __restrict__ src, char* dst, int t) {
#pragma unroll
    for (int i = 0; i < ITERS; ++i) {
        const int idx4 = i * 512 + t;
        const float4 v = *(const float4*)(src + (size_t)idx4 * 4);
        const int r = idx4 / 24, c = (idx4 % 24) * 4;
        uint2 p; p.x = cvtpk(v.x, v.y); p.y = cvtpk(v.z, v.w);
        *(uint2*)(dst + r * 208 + c * 2) = p;
    }
}
__device__ __forceinline__ void stageW(const float* __restrict__ W, char* dst, int t) {
#pragma unroll
    for (int i = 0; i < 5; ++i) {
        const int idx4 = i * 512 + t;
        if (idx4 < 2304) {
            const float4 v = *(const float4*)(W + (size_t)idx4 * 4);
            const int r = idx4 / 24, c = (idx4 % 24) * 4;
            uint2 p; p.x = cvtpk(v.x, v.y); p.y = cvtpk(v.z, v.w);
            *(uint2*)(dst + r * 208 + c * 2) = p;
        }
    }
}

__device__ __forceinline__ void stats512(char* lds_, int t) {
    char* row = lds_ + ((t < 256) ? QL_OFF : QR_OFF) + (t & 255) * 208;
    float sm = 0.f, s2 = 0.f;
#pragma unroll
    for (int i = 0; i < 12; ++i) {
        F8 w; w.q = *(const uint4*)(row + i * 16);
#pragma unroll
        for (int j = 0; j < 4; ++j) {
            const float a = bl(w.u[j]), b = bh(w.u[j]);
            sm += a + b; s2 += a * a + b * b;
        }
    }
    const float mu = sm * (1.f / 96.f);
    float var = s2 * (1.f / 96.f) - mu * mu;
    var = fmaxf(var, 0.f);
    *(float2*)(row + 192) = make_float2(mu, rsqrtf(var + 1e-6f));
}

// In-place LN + Q-projection (W from LDS bf16). Row owned by this wave's lanes.
__device__ __forceinline__ void proj_inplace(char* lds_, int qoff, int woff,
    const float* __restrict__ gv, const float* __restrict__ bv,
    const float* __restrict__ bias1, float outscale, int wv, int l31, int s)
{
    char* row = lds_ + qoff + (wv * 32 + l31) * 208;
    const float2 st = *(const float2*)(row + 192);
    const float mu = st.x, rs = st.y;
    short8 bf[6];
#pragma unroll
    for (int kf = 0; kf < 6; ++kf) {
        const int c0 = kf * 16 + s * 8;
        F8 raw; raw.q = *(const uint4*)(row + c0 * 2);
        const float4 g0 = *(const float4*)(gv + c0);
        const float4 g1 = *(const float4*)(gv + c0 + 4);
        const float4 b0 = *(const float4*)(bv + c0);
        const float4 b1 = *(const float4*)(bv + c0 + 4);
        const float x0=bl(raw.u[0]),x1=bh(raw.u[0]),x2=bl(raw.u[1]),x3=bh(raw.u[1]);
        const float x4=bl(raw.u[2]),x5=bh(raw.u[2]),x6=bl(raw.u[3]),x7=bh(raw.u[3]);
        F8 o;
        o.u[0] = cvtpk((x0-mu)*rs*g0.x + b0.x, (x1-mu)*rs*g0.y + b0.y);
        o.u[1] = cvtpk((x2-mu)*rs*g0.z + b0.z, (x3-mu)*rs*g0.w + b0.w);
        o.u[2] = cvtpk((x4-mu)*rs*g1.x + b1.x, (x5-mu)*rs*g1.y + b1.y);
        o.u[3] = cvtpk((x6-mu)*rs*g1.z + b1.z, (x7-mu)*rs*g1.w + b1.w);
        bf[kf] = o.s;
    }
    f32x16 qa[3];
#pragma unroll
    for (int i = 0; i < 16; ++i) { qa[0][i] = 0.f; qa[1][i] = 0.f; qa[2][i] = 0.f; }
    __builtin_amdgcn_s_setprio(1);
#pragma unroll
    for (int kf = 0; kf < 6; ++kf) {
#pragma unroll
        for (int mf = 0; mf < 3; ++mf) {
            const short8 af = *(const short8*)(lds_ + woff + (mf * 32 + l31) * 208 + kf * 32 + s * 16);
            qa[mf] = MFMA32(af, bf[kf], qa[mf]);
        }
    }
    __builtin_amdgcn_s_setprio(0);
#pragma unroll
    for (int mf = 0; mf < 3; ++mf) {
#pragma unroll
        for (int blk = 0; blk < 4; ++blk) {
            const int d = mf * 32 + blk * 8 + s * 4;
            const float4 bb = *(const float4*)(bias1 + d);
            uint2 p;
            p.x = cvtpk((qa[mf][blk*4+0] + bb.x) * outscale, (qa[mf][blk*4+1] + bb.y) * outscale);
            p.y = cvtpk((qa[mf][blk*4+2] + bb.z) * outscale, (qa[mf][blk*4+3] + bb.w) * outscale);
            *(uint2*)(row + d * 2) = p;
        }
    }
}

__device__ __forceinline__ void vproj(char* lds_, int xt_off, int vt_off,
    const short8* wf, const float* __restrict__ B2, int mfv, int nfv, int l31, int s)
{
    f32x16 va;
#pragma unroll
    for (int i = 0; i < 16; ++i) va[i] = 0.f;
    __builtin_amdgcn_s_setprio(1);
#pragma unroll
    for (int kf = 0; kf < 6; ++kf) {
        const short8 xb = *(const short8*)(lds_ + xt_off + (nfv * 32 + l31) * 208 + kf * 32 + s * 16);
        va = MFMA32(wf[kf], xb, va);
    }
    __builtin_amdgcn_s_setprio(0);
    const int v = nfv * 32 + l31;
#pragma unroll
    for (int blk = 0; blk < 4; ++blk) {
        const int d = mfv * 32 + blk * 8 + s * 4;
        const float4 bb = *(const float4*)(B2 + d);
        *(uint16_t*)(lds_ + vt_off + (d+0) * 144 + v * 2) = (uint16_t)cvtpk(va[blk*4+0] + bb.x, 0.f);
        *(uint16_t*)(lds_ + vt_off + (d+1) * 144 + v * 2) = (uint16_t)cvtpk(va[blk*4+1] + bb.y, 0.f);
        *(uint16_t*)(lds_ + vt_off + (d+2) * 144 + v * 2) = (uint16_t)cvtpk(va[blk*4+2] + bb.z, 0.f);
        *(uint16_t*)(lds_ + vt_off + (d+3) * 144 + v * 2) = (uint16_t)cvtpk(va[blk*4+3] + bb.w, 0.f);
    }
}

__device__ __forceinline__ void scalc(const char* lds_, int koff, int vt,
                                      const short8* bq, int l31, int s, f32x16* sa)
{
#pragma unroll
    for (int i = 0; i < 16; ++i) { sa[0][i] = 0.f; sa[1][i] = 0.f; }
    __builtin_amdgcn_s_setprio(1);
#pragma unroll
    for (int kf = 0; kf < 6; ++kf) {
        const short8 a0 = *(const short8*)(lds_ + koff + (vt * 64 +      l31) * 208 + kf * 32 + s * 16);
        const short8 a1 = *(const short8*)(lds_ + koff + (vt * 64 + 32 + l31) * 208 + kf * 32 + s * 16);
        sa[0] = MFMA32(a0, bq[kf], sa[0]);
        sa[1] = MFMA32(a1, bq[kf], sa[1]);
    }
    __builtin_amdgcn_s_setprio(0);
}

// online softmax in log2 domain + T13 defer-rescale
__device__ __forceinline__ void softmax_tile(f32x16* sa, f32x16* O, float& m_run, float& l_run)
{
    float t0=-1e30f,t1=-1e30f,t2=-1e30f,t3=-1e30f;
#pragma unroll
    for (int i = 0; i < 16; i += 4) {
        t0 = fmaxf(t0, fmaxf(sa[0][i+0], sa[1][i+0]));
        t1 = fmaxf(t1, fmaxf(sa[0][i+1], sa[1][i+1]));
        t2 = fmaxf(t2, fmaxf(sa[0][i+2], sa[1][i+2]));
        t3 = fmaxf(t3, fmaxf(sa[0][i+3], sa[1][i+3]));
    }
    float tm = fmaxf(fmaxf(t0,t1), fmaxf(t2,t3));
    tm = fmaxf(tm, __shfl_xor(tm, 32));
    if (__all(tm - m_run <= 8.f)) {        // defer: P bounded by 2^8
        const float mb = m_run;
        float p0=0.f,p1=0.f,p2=0.f,p3=0.f;
#pragma unroll
        for (int i = 0; i < 16; i += 4) {
            sa[0][i+0]=fexp2(sa[0][i+0]-mb); p0+=sa[0][i+0];
            sa[1][i+0]=fexp2(sa[1][i+0]-mb); p0+=sa[1][i+0];
            sa[0][i+1]=fexp2(sa[0][i+1]-mb); p1+=sa[0][i+1];
            sa[1][i+1]=fexp2(sa[1][i+1]-mb); p1+=sa[1][i+1];
            sa[0][i+2]=fexp2(sa[0][i+2]-mb); p2+=sa[0][i+2];
            sa[1][i+2]=fexp2(sa[1][i+2]-mb); p2+=sa[1][i+2];
            sa[0][i+3]=fexp2(sa[0][i+3]-mb); p3+=sa[0][i+3];
            sa[1][i+3]=fexp2(sa[1][i+3]-mb); p3+=sa[1][i+3];
        }
        float ps = (p0+p1)+(p2+p3);
        ps += __shfl_xor(ps, 32);
        l_run += ps;
    } else {
        const float mn = fmaxf(m_run, tm);
        const float al = fexp2(m_run - mn);
        float p0=0.f,p1=0.f,p2=0.f,p3=0.f;
#pragma unroll
        for (int i = 0; i < 16; i += 4) {
            sa[0][i+0]=fexp2(sa[0][i+0]-mn); p0+=sa[0][i+0];
            sa[1][i+0]=fexp2(sa[1][i+0]-mn); p0+=sa[1][i+0];
            sa[0][i+1]=fexp2(sa[0][i+1]-mn); p1+=sa[0][i+1];
            sa[1][i+1]=fexp2(sa[1][i+1]-mn); p1+=sa[1][i+1];
            sa[0][i+2]=fexp2(sa[0][i+2]-mn); p2+=sa[0][i+2];
            sa[1][i+2]=fexp2(sa[1][i+2]-mn); p2+=sa[1][i+2];
            sa[0][i+3]=fexp2(sa[0][i+3]-mn); p3+=sa[0][i+3];
            sa[1][i+3]=fexp2(sa[1][i+3]-mn); p3+=sa[1][i+3];
        }
        float ps = (p0+p1)+(p2+p3);
        ps += __shfl_xor(ps, 32);
        l_run = l_run * al + ps;
        m_run = mn;
        O[0] *= al; O[1] *= al; O[2] *= al;
    }
}

__device__ __forceinline__ void pv(const char* lds_, int vtoff, f32x16* sa, f32x16* O, int l31, int s)
{
    __builtin_amdgcn_s_setprio(1);
#pragma unroll
    for (int kk = 0; kk < 4; ++kk) {
        const int mf = kk >> 1, base = (kk & 1) * 8;
        const uint32_t A0 = cvtpk(sa[mf][base+0], sa[mf][base+1]);
        const uint32_t A1 = cvtpk(sa[mf][base+2], sa[mf][base+3]);
        const uint32_t B0 = cvtpk(sa[mf][base+4], sa[mf][base+5]);
        const uint32_t B1 = cvtpk(sa[mf][base+6], sa[mf][base+7]);
        const uint32_t rA0 = __shfl_xor(A0, 32);
        const uint32_t rA1 = __shfl_xor(A1, 32);
        const uint32_t rB0 = __shfl_xor(B0, 32);
        const uint32_t rB1 = __shfl_xor(B1, 32);
        F8 pb;
        pb.u[0] = s ? rB0 : A0;
        pb.u[1] = s ? rB1 : A1;
        pb.u[2] = s ? B0  : rA0;
        pb.u[3] = s ? B1  : rA1;
#pragma unroll
        for (int mf2 = 0; mf2 < 3; ++mf2) {
            const short8 av = *(const short8*)(lds_ + vtoff + (mf2 * 32 + l31) * 144 + kk * 32 + s * 16);
            O[mf2] = MFMA32(av, pb.s, O[mf2]);
        }
    }
    __builtin_amdgcn_s_setprio(0);
}

// LDS (160.7KB) pins occupancy at 1 block/CU = 2 waves/EU. Tell the register
// allocator to budget for exactly that (256 regs/wave) instead of its default
// 128-reg target: amdgpu_waves_per_eu(2).
extern "C" __global__ __launch_bounds__(512)
__attribute__((amdgpu_waves_per_eu(2)))
void scam_fused(
    const float* __restrict__ feat_l, const float* __restrict__ feat_r,
    const float* __restrict__ g_nl, const float* __restrict__ b_nl,
    const float* __restrict__ g_nr, const float* __restrict__ b_nr,
    const float* __restrict__ w_l1, const float* __restrict__ bias_l1,
    const float* __restrict__ w_r1, const float* __restrict__ bias_r1,
    const float* __restrict__ w_l2, const float* __restrict__ bias_l2,
    const float* __restrict__ w_r2, const float* __restrict__ bias_r2,
    const float* __restrict__ beta, const float* __restrict__ gamma,
    float* __restrict__ out)
{
    extern __shared__ char lds[];
    const int t    = threadIdx.x;
    const int wv   = t >> 6;
    const int lane = t & 63;
    const int l31  = lane & 31;
    const int s    = lane >> 5;
    const size_t eb = (size_t)blockIdx.x * (256 * C96);
    // 96^-0.5 * log2(e): S in log2 domain, folded once into stored Q_l
    const float scale = 0.10206207261596577f * 1.4426950408889634f;

    // ================= phase 1: both Q projections =================
    stage<12>(feat_l + eb, lds + QL_OFF, t);
    stage<12>(feat_r + eb, lds + QR_OFF, t);
    stageW(w_l1, lds + W1Q_OFF, t);
    stageW(w_r1, lds + W1K_OFF, t);
    __syncthreads();
    stats512(lds, t);
    __syncthreads();
    proj_inplace(lds, QL_OFF, W1Q_OFF, g_nl, b_nl, bias_l1, scale, wv, l31, s);
    proj_inplace(lds, QR_OFF, W1K_OFF, g_nr, b_nr, bias_r1, 1.0f,  wv, l31, s);
    __syncthreads();        // W1 regions free; Q rows visible to all waves

    // ================= phase 2: dual-direction flash attention =================
    for (int dir = 0; dir < 2; ++dir) {
        const int qoff = dir ? QR_OFF : QL_OFF;
        const int koff = dir ? QL_OFF : QR_OFF;
        const float* Xk   = dir ? feat_l  : feat_r;
        const float* Xq   = dir ? feat_r  : feat_l;
        const float* W2   = dir ? w_l2    : w_r2;
        const float* B2   = dir ? bias_l2 : bias_r2;
        const float* mixv = dir ? gamma   : beta;

        float4 A0, A1, A2;
        stage_issue(Xk + eb, t, A0, A1, A2);           // tile 0

        short8 bq[6];
#pragma unroll
        for (int kf = 0; kf < 6; ++kf)
            bq[kf] = *(const short8*)(lds + qoff + (wv * 32 + l31) * 208 + kf * 32 + s * 16);

        short8 wf[6];
        const int mfv = wv % 3, nfv = wv / 3;
        if (wv < 6) {
#pragma unroll
            for (int kf = 0; kf < 6; ++kf) {
                const float* wp = W2 + (mfv * 32 + l31) * 96 + kf * 16 + s * 8;
                const float4 a0 = *(const float4*)wp;
                const float4 a1 = *(const float4*)(wp + 4);
                F8 af;
                af.u[0] = cvtpk(a0.x, a0.y); af.u[1] = cvtpk(a0.z, a0.w);
                af.u[2] = cvtpk(a1.x, a1.y); af.u[3] = cvtpk(a1.z, a1.w);
                wf[kf] = af.s;
            }
        }

        stage_commit(lds + XT0_OFF, t, A0, A1, A2);
        __syncthreads();                                // B1: XT0 visible
        if (wv < 6) vproj(lds, XT0_OFF, VT0_OFF, wf, B2, mfv, nfv, l31, s);
        stage_issue(Xk + eb + 64 * 96, t, A0, A1, A2);  // tile 1
        stage_commit(lds + XT1_OFF, t, A0, A1, A2);
        __syncthreads();                                // B2: VT0 + XT1 visible

        f32x16 O[3];
#pragma unroll
        for (int i = 0; i < 16; ++i) { O[0][i] = 0.f; O[1][i] = 0.f; O[2][i] = 0.f; }
        float m_run = -1e30f, l_run = 0.f;
        f32x16 sa0[2], sa1[2];
        scalc(lds, koff, 0, bq, l31, s, sa0);

        // ---- vt=0 ----
        stage_issue(Xk + eb + 2 * 64 * 96, t, A0, A1, A2);   // tile 2
        scalc(lds, koff, 1, bq, l31, s, sa1);
        softmax_tile(sa0, O, m_run, l_run);
        if (wv < 6) vproj(lds, XT1_OFF, VT1_OFF, wf, B2, mfv, nfv, l31, s);
        pv(lds, VT0_OFF, sa0, O, l31, s);
        stage_commit(lds + XT0_OFF, t, A0, A1, A2);
        __syncthreads();
        // ---- vt=1 ----
        stage_issue(Xk + eb + 3 * 64 * 96, t, A0, A1, A2);   // tile 3
        scalc(lds, koff, 2, bq, l31, s, sa0);
        softmax_tile(sa1, O, m_run, l_run);
        if (wv < 6) vproj(lds, XT0_OFF, VT0_OFF, wf, B2, mfv, nfv, l31, s);
        pv(lds, VT1_OFF, sa1, O, l31, s);
        stage_commit(lds + XT1_OFF, t, A0, A1, A2);
        __syncthreads();
        // ---- vt=2 ----
        scalc(lds, koff, 3, bq, l31, s, sa1);
        softmax_tile(sa0, O, m_run, l_run);
        if (wv < 6) vproj(lds, XT1_OFF, VT1_OFF, wf, B2, mfv, nfv, l31, s);
        pv(lds, VT0_OFF, sa0, O, l31, s);
        __syncthreads();
        // ---- vt=3 ----
        softmax_tile(sa1, O, m_run, l_run);
        pv(lds, VT1_OFF, sa1, O, l31, s);

        // ---- epilogue: out = x_res + (O/l) * mix ----
        const float inv = 1.f / l_run;
        const size_t rowbase = eb + (size_t)(wv * 32 + l31) * 96;
        float* oo = out + (dir ? TOTEL : 0);
#pragma unroll
        for (int mf = 0; mf < 3; ++mf) {
#pragma unroll
            for (int blk = 0; blk < 4; ++blk) {
                const int d = mf * 32 + blk * 8 + s * 4;
                const float4 mx = *(const float4*)(mixv + d);
                const float4 rv = *(const float4*)(Xq + rowbase + d);
                float4 ov;
                ov.x = fmaf(O[mf][blk*4+0] * inv, mx.x, rv.x);
                ov.y = fmaf(O[mf][blk*4+1] * inv, mx.y, rv.y);
                ov.z = fmaf(O[mf][blk*4+2] * inv, mx.z, rv.z);
                ov.w = fmaf(O[mf][blk*4+3] * inv, mx.w, rv.w);
                *(float4*)(oo + rowbase + d) = ov;
            }
        }
    }
}

extern "C" void kernel_launch(void* const* d_in, const int* in_sizes, int n_in,
                              void* d_out, int out_size, void* d_ws, size_t ws_size,
                              hipStream_t stream) {
    const float* feat_l  = (const float*)d_in[0];
    const float* feat_r  = (const float*)d_in[1];
    const float* g_nl    = (const float*)d_in[2];
    const float* b_nl    = (const float*)d_in[3];
    const float* g_nr    = (const float*)d_in[4];
    const float* b_nr    = (const float*)d_in[5];
    const float* w_l1    = (const float*)d_in[6];
    const float* bias_l1 = (const float*)d_in[7];
    const float* w_r1    = (const float*)d_in[8];
    const float* bias_r1 = (const float*)d_in[9];
    const float* w_l2    = (const float*)d_in[10];
    const float* bias_l2 = (const float*)d_in[11];
    const float* w_r2    = (const float*)d_in[12];
    const float* bias_r2 = (const float*)d_in[13];
    const float* beta    = (const float*)d_in[14];
    const float* gamma   = (const float*)d_in[15];
    float* out = (float*)d_out;

    hipLaunchKernelGGL(scam_fused, dim3(1024), dim3(512), LDS_SZ, stream,
                       feat_l, feat_r, g_nl, b_nl, g_nr, b_nr,
                       w_l1, bias_l1, w_r1, bias_r1, w_l2, bias_l2, w_r2, bias_r2,
                       beta, gamma, out);
}

// Round 8
// 226.440 us; speedup vs baseline: 1.3198x; 1.3198x over previous
//
#include <hip/hip_runtime.h>
#include <stdint.h>

#define C96   96
#define TOTEL 25165824L   // 8*128*256*96

typedef __attribute__((ext_vector_type(16))) float f32x16;
typedef __attribute__((ext_vector_type(8)))  short short8;

// ---- LDS layout (bytes). Tile rows stride 208 B (104 bf16). Pad [192..207]={mu,rs}.
#define QL_OFF  0         // Q_l (raw X_l during stage) [256][208] = 53248
#define QR_OFF  53248     // Q_r [256][208] = 53248
#define XT0_OFF 106496    // raw V-source tile buf0 [64][208] = 13312
#define XT1_OFF 119808    // buf1
#define VT0_OFF 133120    // V^T bf16 [96][144B] = 13824, buf0
#define VT1_OFF 146944    // buf1 -> end 160768
// phase-1 overlay (temporally disjoint):
#define W1Q_OFF 106496    // W1 q-side bf16 [96][208]
#define W1K_OFF 126464    // W1 K-side bf16 [96][208]
#define LDS_SZ  160768

#define MFMA32(a,b,c) __builtin_amdgcn_mfma_f32_32x32x16_bf16(a,b,c,0,0,0)

__device__ __forceinline__ uint32_t cvtpk(float lo, float hi) {
    uint32_t d;
    asm("v_cvt_pk_bf16_f32 %0, %1, %2" : "=v"(d) : "v"(lo), "v"(hi));
    return d;
}
__device__ __forceinline__ float fexp2(float x) {       // v_exp_f32 computes 2^x
    float r; asm("v_exp_f32 %0, %1" : "=v"(r) : "v"(x)); return r;
}
__device__ __forceinline__ float bl(uint32_t u){ union{uint32_t i;float f;}a; a.i=u<<16;        return a.f; }
__device__ __forceinline__ float bh(uint32_t u){ union{uint32_t i;float f;}a; a.i=u&0xffff0000u; return a.f; }

union F8 { uint32_t u[4]; short8 s; uint4 q; };

// coalesced global f32 -> LDS bf16 rows (stride 208 B); load + immediate commit
template<int ITERS>
__device__ __forceinline__ void stage(const float* __restrict__ src, char* dst, int t) {
#pragma unroll
    for (int i = 0; i < ITERS; ++i) {
        const int idx4 = i * 512 + t;
        const float4 v = *(const float4*)(src + (size_t)idx4 * 4);
        const int r = idx4 / 24, c = (idx4 % 24) * 4;
        uint2 p; p.x = cvtpk(v.x, v.y); p.y = cvtpk(v.z, v.w);
        *(uint2*)(dst + r * 208 + c * 2) = p;
    }
}
__device__ __forceinline__ void stageW(const float* __restrict__ W, char* dst, int t) {
#pragma unroll
    for (int i = 0; i < 5; ++i) {
        const int idx4 = i * 512 + t;
        if (idx4 < 2304) {
            const float4 v = *(const float4*)(W + (size_t)idx4 * 4);
            const int r = idx4 / 24, c = (idx4 % 24) * 4;
            uint2 p; p.x = cvtpk(v.x, v.y); p.y = cvtpk(v.z, v.w);
            *(uint2*)(dst + r * 208 + c * 2) = p;
        }
    }
}

__device__ __forceinline__ void stats512(char* lds_, int t) {
    char* row = lds_ + ((t < 256) ? QL_OFF : QR_OFF) + (t & 255) * 208;
    float sm = 0.f, s2 = 0.f;
#pragma unroll
    for (int i = 0; i < 12; ++i) {
        F8 w; w.q = *(const uint4*)(row + i * 16);
#pragma unroll
        for (int j = 0; j < 4; ++j) {
            const float a = bl(w.u[j]), b = bh(w.u[j]);
            sm += a + b; s2 += a * a + b * b;
        }
    }
    const float mu = sm * (1.f / 96.f);
    float var = s2 * (1.f / 96.f) - mu * mu;
    var = fmaxf(var, 0.f);
    *(float2*)(row + 192) = make_float2(mu, rsqrtf(var + 1e-6f));
}

// In-place LN + Q-projection (W from LDS bf16). Row owned by this wave's lanes.
__device__ __forceinline__ void proj_inplace(char* lds_, int qoff, int woff,
    const float* __restrict__ gv, const float* __restrict__ bv,
    const float* __restrict__ bias1, float outscale, int wv, int l31, int s)
{
    char* row = lds_ + qoff + (wv * 32 + l31) * 208;
    const float2 st = *(const float2*)(row + 192);
    const float mu = st.x, rs = st.y;
    short8 bf[6];
#pragma unroll
    for (int kf = 0; kf < 6; ++kf) {
        const int c0 = kf * 16 + s * 8;
        F8 raw; raw.q = *(const uint4*)(row + c0 * 2);
        const float4 g0 = *(const float4*)(gv + c0);
        const float4 g1 = *(const float4*)(gv + c0 + 4);
        const float4 b0 = *(const float4*)(bv + c0);
        const float4 b1 = *(const float4*)(bv + c0 + 4);
        const float x0=bl(raw.u[0]),x1=bh(raw.u[0]),x2=bl(raw.u[1]),x3=bh(raw.u[1]);
        const float x4=bl(raw.u[2]),x5=bh(raw.u[2]),x6=bl(raw.u[3]),x7=bh(raw.u[3]);
        F8 o;
        o.u[0] = cvtpk((x0-mu)*rs*g0.x + b0.x, (x1-mu)*rs*g0.y + b0.y);
        o.u[1] = cvtpk((x2-mu)*rs*g0.z + b0.z, (x3-mu)*rs*g0.w + b0.w);
        o.u[2] = cvtpk((x4-mu)*rs*g1.x + b1.x, (x5-mu)*rs*g1.y + b1.y);
        o.u[3] = cvtpk((x6-mu)*rs*g1.z + b1.z, (x7-mu)*rs*g1.w + b1.w);
        bf[kf] = o.s;
    }
    f32x16 qa[3];
#pragma unroll
    for (int i = 0; i < 16; ++i) { qa[0][i] = 0.f; qa[1][i] = 0.f; qa[2][i] = 0.f; }
    __builtin_amdgcn_s_setprio(1);
#pragma unroll
    for (int kf = 0; kf < 6; ++kf) {
#pragma unroll
        for (int mf = 0; mf < 3; ++mf) {
            const short8 af = *(const short8*)(lds_ + woff + (mf * 32 + l31) * 208 + kf * 32 + s * 16);
            qa[mf] = MFMA32(af, bf[kf], qa[mf]);
        }
    }
    __builtin_amdgcn_s_setprio(0);
#pragma unroll
    for (int mf = 0; mf < 3; ++mf) {
#pragma unroll
        for (int blk = 0; blk < 4; ++blk) {
            const int d = mf * 32 + blk * 8 + s * 4;
            const float4 bb = *(const float4*)(bias1 + d);
            uint2 p;
            p.x = cvtpk((qa[mf][blk*4+0] + bb.x) * outscale, (qa[mf][blk*4+1] + bb.y) * outscale);
            p.y = cvtpk((qa[mf][blk*4+2] + bb.z) * outscale, (qa[mf][blk*4+3] + bb.w) * outscale);
            *(uint2*)(row + d * 2) = p;
        }
    }
}

// V projection for one 64-row tile: V^T[d][v] from raw XT buffer
__device__ __forceinline__ void vproj(char* lds_, int xt_off, int vt_off,
    const short8* wf, const float* __restrict__ B2, int mfv, int nfv, int l31, int s)
{
    f32x16 va;
#pragma unroll
    for (int i = 0; i < 16; ++i) va[i] = 0.f;
    __builtin_amdgcn_s_setprio(1);
#pragma unroll
    for (int kf = 0; kf < 6; ++kf) {
        const short8 xb = *(const short8*)(lds_ + xt_off + (nfv * 32 + l31) * 208 + kf * 32 + s * 16);
        va = MFMA32(wf[kf], xb, va);
    }
    __builtin_amdgcn_s_setprio(0);
    const int v = nfv * 32 + l31;
#pragma unroll
    for (int blk = 0; blk < 4; ++blk) {
        const int d = mfv * 32 + blk * 8 + s * 4;
        const float4 bb = *(const float4*)(B2 + d);
        *(uint16_t*)(lds_ + vt_off + (d+0) * 144 + v * 2) = (uint16_t)cvtpk(va[blk*4+0] + bb.x, 0.f);
        *(uint16_t*)(lds_ + vt_off + (d+1) * 144 + v * 2) = (uint16_t)cvtpk(va[blk*4+1] + bb.y, 0.f);
        *(uint16_t*)(lds_ + vt_off + (d+2) * 144 + v * 2) = (uint16_t)cvtpk(va[blk*4+2] + bb.z, 0.f);
        *(uint16_t*)(lds_ + vt_off + (d+3) * 144 + v * 2) = (uint16_t)cvtpk(va[blk*4+3] + bb.w, 0.f);
    }
}

// S^T tile (both 32-row halves) from K-region + cached bq
__device__ __forceinline__ void scalc(const char* lds_, int koff, int vt,
                                      const short8* bq, int l31, int s, f32x16* sa)
{
#pragma unroll
    for (int i = 0; i < 16; ++i) { sa[0][i] = 0.f; sa[1][i] = 0.f; }
    __builtin_amdgcn_s_setprio(1);
#pragma unroll
    for (int kf = 0; kf < 6; ++kf) {
        const short8 a0 = *(const short8*)(lds_ + koff + (vt * 64 +      l31) * 208 + kf * 32 + s * 16);
        const short8 a1 = *(const short8*)(lds_ + koff + (vt * 64 + 32 + l31) * 208 + kf * 32 + s * 16);
        sa[0] = MFMA32(a0, bq[kf], sa[0]);
        sa[1] = MFMA32(a1, bq[kf], sa[1]);
    }
    __builtin_amdgcn_s_setprio(0);
}

// online softmax in log2 domain + T13 defer-rescale (zero extra registers)
__device__ __forceinline__ void softmax_tile(f32x16* sa, f32x16* O, float& m_run, float& l_run)
{
    float t0=-1e30f,t1=-1e30f,t2=-1e30f,t3=-1e30f;
#pragma unroll
    for (int i = 0; i < 16; i += 4) {
        t0 = fmaxf(t0, fmaxf(sa[0][i+0], sa[1][i+0]));
        t1 = fmaxf(t1, fmaxf(sa[0][i+1], sa[1][i+1]));
        t2 = fmaxf(t2, fmaxf(sa[0][i+2], sa[1][i+2]));
        t3 = fmaxf(t3, fmaxf(sa[0][i+3], sa[1][i+3]));
    }
    float tm = fmaxf(fmaxf(t0,t1), fmaxf(t2,t3));
    tm = fmaxf(tm, __shfl_xor(tm, 32));
    const bool defer = __all(tm - m_run <= 8.f);   // P bounded by 2^8: bf16-safe
    const float mn = defer ? m_run : fmaxf(m_run, tm);
    float p0=0.f,p1=0.f,p2=0.f,p3=0.f;
#pragma unroll
    for (int i = 0; i < 16; i += 4) {
        sa[0][i+0]=fexp2(sa[0][i+0]-mn); p0+=sa[0][i+0];
        sa[1][i+0]=fexp2(sa[1][i+0]-mn); p0+=sa[1][i+0];
        sa[0][i+1]=fexp2(sa[0][i+1]-mn); p1+=sa[0][i+1];
        sa[1][i+1]=fexp2(sa[1][i+1]-mn); p1+=sa[1][i+1];
        sa[0][i+2]=fexp2(sa[0][i+2]-mn); p2+=sa[0][i+2];
        sa[1][i+2]=fexp2(sa[1][i+2]-mn); p2+=sa[1][i+2];
        sa[0][i+3]=fexp2(sa[0][i+3]-mn); p3+=sa[0][i+3];
        sa[1][i+3]=fexp2(sa[1][i+3]-mn); p3+=sa[1][i+3];
    }
    float ps = (p0+p1)+(p2+p3);
    ps += __shfl_xor(ps, 32);
    if (defer) {
        l_run += ps;
    } else {
        const float al = fexp2(m_run - mn);
        l_run = l_run * al + ps;
        m_run = mn;
        O[0] *= al; O[1] *= al; O[2] *= al;
    }
}

__device__ __forceinline__ void pv(const char* lds_, int vtoff, f32x16* sa, f32x16* O, int l31, int s)
{
    __builtin_amdgcn_s_setprio(1);
#pragma unroll
    for (int kk = 0; kk < 4; ++kk) {
        const int mf = kk >> 1, base = (kk & 1) * 8;
        const uint32_t A0 = cvtpk(sa[mf][base+0], sa[mf][base+1]);
        const uint32_t A1 = cvtpk(sa[mf][base+2], sa[mf][base+3]);
        const uint32_t B0 = cvtpk(sa[mf][base+4], sa[mf][base+5]);
        const uint32_t B1 = cvtpk(sa[mf][base+6], sa[mf][base+7]);
        const uint32_t rA0 = __shfl_xor(A0, 32);
        const uint32_t rA1 = __shfl_xor(A1, 32);
        const uint32_t rB0 = __shfl_xor(B0, 32);
        const uint32_t rB1 = __shfl_xor(B1, 32);
        F8 pb;
        pb.u[0] = s ? rB0 : A0;
        pb.u[1] = s ? rB1 : A1;
        pb.u[2] = s ? B0  : rA0;
        pb.u[3] = s ? B1  : rA1;
#pragma unroll
        for (int mf2 = 0; mf2 < 3; ++mf2) {
            const short8 av = *(const short8*)(lds_ + vtoff + (mf2 * 32 + l31) * 144 + kk * 32 + s * 16);
            O[mf2] = MFMA32(av, pb.s, O[mf2]);
        }
    }
    __builtin_amdgcn_s_setprio(0);
}

// Arch-VGPR budget is hard-capped at 128 (accumulators live in the AGPR half
// of the unified file). The R4 schedule fits; do not add long-lived registers.
extern "C" __global__ __launch_bounds__(512, 2) void scam_fused(
    const float* __restrict__ feat_l, const float* __restrict__ feat_r,
    const float* __restrict__ g_nl, const float* __restrict__ b_nl,
    const float* __restrict__ g_nr, const float* __restrict__ b_nr,
    const float* __restrict__ w_l1, const float* __restrict__ bias_l1,
    const float* __restrict__ w_r1, const float* __restrict__ bias_r1,
    const float* __restrict__ w_l2, const float* __restrict__ bias_l2,
    const float* __restrict__ w_r2, const float* __restrict__ bias_r2,
    const float* __restrict__ beta, const float* __restrict__ gamma,
    float* __restrict__ out)
{
    extern __shared__ char lds[];
    const int t    = threadIdx.x;
    const int wv   = t >> 6;
    const int lane = t & 63;
    const int l31  = lane & 31;
    const int s    = lane >> 5;
    const size_t eb = (size_t)blockIdx.x * (256 * C96);
    // 96^-0.5 * log2(e): S computed in log2 domain (v_exp_f32 is base-2)
    const float scale = 0.10206207261596577f * 1.4426950408889634f;

    // ================= phase 1: both Q projections =================
    stage<12>(feat_l + eb, lds + QL_OFF, t);
    stage<12>(feat_r + eb, lds + QR_OFF, t);
    stageW(w_l1, lds + W1Q_OFF, t);
    stageW(w_r1, lds + W1K_OFF, t);
    __syncthreads();
    stats512(lds, t);
    __syncthreads();
    proj_inplace(lds, QL_OFF, W1Q_OFF, g_nl, b_nl, bias_l1, scale, wv, l31, s);
    proj_inplace(lds, QR_OFF, W1K_OFF, g_nr, b_nr, bias_r1, 1.0f,  wv, l31, s);

    // ================= phase 2: dual-direction flash attention =================
    for (int dir = 0; dir < 2; ++dir) {
        const int qoff = dir ? QR_OFF : QL_OFF;
        const int koff = dir ? QL_OFF : QR_OFF;
        const float* Xk   = dir ? feat_l  : feat_r;
        const float* Xq   = dir ? feat_r  : feat_l;
        const float* W2   = dir ? w_l2    : w_r2;
        const float* B2   = dir ? bias_l2 : bias_r2;
        const float* mixv = dir ? gamma   : beta;

        short8 bq[6];
#pragma unroll
        for (int kf = 0; kf < 6; ++kf)
            bq[kf] = *(const short8*)(lds + qoff + (wv * 32 + l31) * 208 + kf * 32 + s * 16);

        short8 wf[6];
        const int mfv = wv % 3, nfv = wv / 3;
        if (wv < 6) {
#pragma unroll
            for (int kf = 0; kf < 6; ++kf) {
                const float* wp = W2 + (mfv * 32 + l31) * 96 + kf * 16 + s * 8;
                const float4 a0 = *(const float4*)wp;
                const float4 a1 = *(const float4*)(wp + 4);
                F8 af;
                af.u[0] = cvtpk(a0.x, a0.y); af.u[1] = cvtpk(a0.z, a0.w);
                af.u[2] = cvtpk(a1.x, a1.y); af.u[3] = cvtpk(a1.z, a1.w);
                wf[kf] = af.s;
            }
        }

        f32x16 O[3];
#pragma unroll
        for (int i = 0; i < 16; ++i) { O[0][i] = 0.f; O[1][i] = 0.f; O[2][i] = 0.f; }
        float m_run = -1e30f, l_run = 0.f;
        f32x16 sab[2][2];

        __syncthreads();                 // boundary: phase1 W-reads / prev-dir VT reads done
        stage<3>(Xk + eb, lds + XT0_OFF, t);
        __syncthreads();                 // XT0 ready
        if (wv < 6) vproj(lds, XT0_OFF, VT0_OFF, wf, B2, mfv, nfv, l31, s);
        stage<3>(Xk + eb + 64 * 96, lds + XT1_OFF, t);
        __syncthreads();                 // VT0 + XT1 ready
        scalc(lds, koff, 0, bq, l31, s, sab[0]);

#pragma unroll
        for (int vt = 0; vt < 4; ++vt) {
            const int cb = vt & 1, nb = cb ^ 1;
            if (vt < 3) scalc(lds, koff, vt + 1, bq, l31, s, sab[nb]);  // overlaps softmax below

            f32x16* sa = sab[cb];
            softmax_tile(sa, O, m_run, l_run);

            // ---- PV: O^T += V^T * P^T ----
            pv(lds, cb ? VT1_OFF : VT0_OFF, sa, O, l31, s);

            if (vt < 3) {
                __syncthreads();         // PV(vt) done; VT[nb] free; XT[nb] staged
                if (wv < 6) vproj(lds, nb ? XT1_OFF : XT0_OFF, nb ? VT1_OFF : VT0_OFF,
                                  wf, B2, mfv, nfv, l31, s);
                if (vt < 2) stage<3>(Xk + eb + (size_t)(vt + 2) * 64 * 96,
                                     lds + (cb ? XT1_OFF : XT0_OFF), t);
                __syncthreads();         // VT[nb] visible; XT(vt+2) staged
            }
        }

        // ---- epilogue: out = x_res + (O/l) * mix ----
        const float inv = 1.f / l_run;
        const size_t rowbase = eb + (size_t)(wv * 32 + l31) * 96;
        float* oo = out + (dir ? TOTEL : 0);
#pragma unroll
        for (int mf = 0; mf < 3; ++mf) {
#pragma unroll
            for (int blk = 0; blk < 4; ++blk) {
                const int d = mf * 32 + blk * 8 + s * 4;
                const float4 mx = *(const float4*)(mixv + d);
                const float4 xr = *(const float4*)(Xq + rowbase + d);
                float4 ov;
                ov.x = fmaf(O[mf][blk*4+0] * inv, mx.x, xr.x);
                ov.y = fmaf(O[mf][blk*4+1] * inv, mx.y, xr.y);
                ov.z = fmaf(O[mf][blk*4+2] * inv, mx.z, xr.z);
                ov.w = fmaf(O[mf][blk*4+3] * inv, mx.w, xr.w);
                *(float4*)(oo + rowbase + d) = ov;
            }
        }
    }
}

extern "C" void kernel_launch(void* const* d_in, const int* in_sizes, int n_in,
                              void* d_out, int out_size, void* d_ws, size_t ws_size,
                              hipStream_t stream) {
    const float* feat_l  = (const float*)d_in[0];
    const float* feat_r  = (const float*)d_in[1];
    const float* g_nl    = (const float*)d_in[2];
    const float* b_nl    = (const float*)d_in[3];
    const float* g_nr    = (const float*)d_in[4];
    const float* b_nr    = (const float*)d_in[5];
    const float* w_l1    = (const float*)d_in[6];
    const float* bias_l1 = (const float*)d_in[7];
    const float* w_r1    = (const float*)d_in[8];
    const float* bias_r1 = (const float*)d_in[9];
    const float* w_l2    = (const float*)d_in[10];
    const float* bias_l2 = (const float*)d_in[11];
    const float* w_r2    = (const float*)d_in[12];
    const float* bias_r2 = (const float*)d_in[13];
    const float* beta    = (const float*)d_in[14];
    const float* gamma   = (const float*)d_in[15];
    float* out = (float*)d_out;

    hipLaunchKernelGGL(scam_fused, dim3(1024), dim3(512), LDS_SZ, stream,
                       feat_l, feat_r, g_nl, b_nl, g_nr, b_nr,
                       w_l1, bias_l1, w_r1, bias_r1, w_l2, bias_l2, w_r2, bias_r2,
                       beta, gamma, out);
}